// Round 7
// baseline (293.296 us; speedup 1.0000x reference)
//
#include <hip/hip_runtime.h>
#include <hip/hip_bf16.h>

// Self-attention: q=X@Wq.T+bq, k=..., v=...; S = causal_softmax(q k^T / 32); O = S v
// B=4, S=2048, D_IN=D_OUT=1024. fp32 in/out; internal compute bf16 MFMA + fp32 acc.
//
// R7 change: scores & pv rewritten as WAVE-AUTONOMOUS kernels — 64-thread
// (single-wave) workgroups, 64x64 tiles. With one wave per workgroup the
// barrier is wave-local (no cross-wave vmcnt coupling) and ~16 independent
// waves/CU hide each other's staging drains (m114 co-scheduling). Fixes R6's
// diagnosis: pv had Occupancy 5.97% (256 blocks x 4 waves, 1 block/CU) and
// MfmaUtil 9.9%. pv dispatches longest-K blocks first (reversed m index).
// qkv kept at R4's 128x128 3-fused form (best measured).
//
// MFMA fragment layouts (HW-verified per guide §3):
//  A: lane holds A[m=lane&15][k=(lane>>4)*8+j], j=0..7
//  B: lane holds B[k=(lane>>4)*8+j][n=lane&15]
//  C/D: lane holds D[row=(lane>>4)*4+e][col=lane&15], e=0..3

typedef __attribute__((ext_vector_type(8))) short short8;   // 8 bf16 = 4 VGPRs
typedef __attribute__((ext_vector_type(4))) float floatx4;  // MFMA acc

#define SEQ   2048
#define DMODEL 1024
#define NBATCH 4
#define MTOT  (SEQ * NBATCH)

// Direct global->LDS async copy, 16B per lane. LDS dst is wave-uniform base +
// lane*16 (per-lane scatter NOT supported) — our tile layout is lane-contiguous.
__device__ __forceinline__ void stage16(const __hip_bfloat16* g, __hip_bfloat16* l)
{
  __builtin_amdgcn_global_load_lds(
      (const __attribute__((address_space(1))) void*)g,
      (__attribute__((address_space(3))) void*)l, 16, 0, 0);
}

__device__ __forceinline__ unsigned short bf16_bits(float f)
{
  __hip_bfloat16 h = __float2bfloat16(f);
  return *(unsigned short*)&h;
}

// ---------------------------------------------------------------------------
// One-kernel fp32 -> bf16 convert for all four inputs. Each block: 1024 elems.
__global__ __launch_bounds__(256) void convert_all(
    const float* __restrict__ X,  const float* __restrict__ Wq,
    const float* __restrict__ Wk, const float* __restrict__ Wv,
    __hip_bfloat16* __restrict__ Xb,  __hip_bfloat16* __restrict__ Wqb,
    __hip_bfloat16* __restrict__ Wkb, __hip_bfloat16* __restrict__ Wvb)
{
  const int b = blockIdx.x;
  const float* src; __hip_bfloat16* dst; int rel;
  if (b < 8192)       { src = X;  dst = Xb;  rel = b; }
  else if (b < 9216)  { src = Wq; dst = Wqb; rel = b - 8192; }
  else if (b < 10240) { src = Wk; dst = Wkb; rel = b - 9216; }
  else                { src = Wv; dst = Wvb; rel = b - 10240; }
  const int i = rel * 1024 + threadIdx.x * 4;
  float4 f = *(const float4*)(src + i);
  uint2 o;
  o.x = (unsigned)bf16_bits(f.x) | ((unsigned)bf16_bits(f.y) << 16);
  o.y = (unsigned)bf16_bits(f.z) | ((unsigned)bf16_bits(f.w) << 16);
  *(uint2*)(dst + i) = o;
}

// ---------------------------------------------------------------------------
// Fused QKV projection (R4 version, best measured). A-tile (X) staged once per
// k-iter, three 128x32 B-tiles; 48 MFMA/wave/barrier. Q,K row-major; V -> Vt.
// grid = (8, 64), 256 threads, 32 KB LDS.
__global__ __launch_bounds__(256, 2) void gemm_qkv_fused(
    const __hip_bfloat16* __restrict__ Xb,
    const __hip_bfloat16* __restrict__ Wqb,
    const __hip_bfloat16* __restrict__ Wkb,
    const __hip_bfloat16* __restrict__ Wvb,
    const float* __restrict__ bq, const float* __restrict__ bk, const float* __restrict__ bv,
    __hip_bfloat16* __restrict__ Qb, __hip_bfloat16* __restrict__ Kb, __hip_bfloat16* __restrict__ Vt)
{
  __shared__ __hip_bfloat16 As[128 * 32];
  __shared__ __hip_bfloat16 Bs[3][128 * 32];
  const int m0 = blockIdx.y * 128, n0 = blockIdx.x * 128;
  const int tid  = threadIdx.x;
  const int lane = tid & 63;
  const int wave = tid >> 6;
  const int quad = lane >> 4;
  const int r    = lane & 15;
  const int wm   = (wave >> 1) * 64;
  const int wn   = (wave & 1) * 64;
  const int srow = wave * 16 + (lane >> 2);   // 0..63
  const int scol = (lane & 3) * 8;            // 0,8,16,24

  const __hip_bfloat16* Wp[3] = {Wqb, Wkb, Wvb};

  __hip_bfloat16* lA0 = As + wave * 512;
  __hip_bfloat16* lA1 = As + 2048 + wave * 512;

  const __hip_bfloat16* aR0 = Xb + (size_t)(m0 + srow) * DMODEL + scol;
  const __hip_bfloat16* aR1 = aR0 + (size_t)64 * DMODEL;

  floatx4 acc[3][4][4] = {};

  for (int kt = 0; kt < DMODEL / 32; ++kt) {
    const int k0 = kt * 32;
    stage16(aR0 + k0, lA0);
    stage16(aR1 + k0, lA1);
#pragma unroll
    for (int w = 0; w < 3; ++w) {
      stage16(Wp[w] + (size_t)(n0 + srow) * DMODEL + scol + k0,      Bs[w] + wave * 512);
      stage16(Wp[w] + (size_t)(n0 + 64 + srow) * DMODEL + scol + k0, Bs[w] + 2048 + wave * 512);
    }
    __syncthreads();
    short8 a[4];
#pragma unroll
    for (int i = 0; i < 4; ++i)
      a[i] = *(const short8*)(As + (wm + i * 16 + r) * 32 + quad * 8);
#pragma unroll
    for (int w = 0; w < 3; ++w) {
      short8 b[4];
#pragma unroll
      for (int j = 0; j < 4; ++j)
        b[j] = *(const short8*)(Bs[w] + (wn + j * 16 + r) * 32 + quad * 8);
#pragma unroll
      for (int i = 0; i < 4; ++i)
#pragma unroll
        for (int j = 0; j < 4; ++j)
          acc[w][i][j] = __builtin_amdgcn_mfma_f32_16x16x32_bf16(a[i], b[j], acc[w][i][j], 0, 0, 0);
    }
    __syncthreads();
  }

  // Q, K: row-major stores
  {
    __hip_bfloat16* Op[2] = {Qb, Kb};
    const float* Bp[2] = {bq, bk};
#pragma unroll
    for (int w = 0; w < 2; ++w) {
      __hip_bfloat16* out = Op[w];
#pragma unroll
      for (int j = 0; j < 4; ++j) {
        const int n = n0 + wn + j * 16 + r;
        const float bb = Bp[w][n];
#pragma unroll
        for (int i = 0; i < 4; ++i) {
          const int mbase = m0 + wm + i * 16 + quad * 4;
#pragma unroll
          for (int e = 0; e < 4; ++e)
            out[(size_t)(mbase + e) * DMODEL + n] = __float2bfloat16(acc[w][i][j][e] + bb);
        }
      }
    }
  }
  // V: transposed store Vt[z][d=n][pos], 8B packed per (i,j). z = batch of m0.
  {
    const int z    = m0 >> 11;           // SEQ = 2048
    const int posb = (m0 & (SEQ - 1)) + wm;
    __hip_bfloat16* vt = Vt + (size_t)z * DMODEL * SEQ;
#pragma unroll
    for (int j = 0; j < 4; ++j) {
      const int n = n0 + wn + j * 16 + r;
      const float bb = bv[n];
#pragma unroll
      for (int i = 0; i < 4; ++i) {
        const int pos = posb + i * 16 + quad * 4;
        unsigned long long pk =
            (unsigned long long)bf16_bits(acc[2][i][j][0] + bb)
          | ((unsigned long long)bf16_bits(acc[2][i][j][1] + bb) << 16)
          | ((unsigned long long)bf16_bits(acc[2][i][j][2] + bb) << 32)
          | ((unsigned long long)bf16_bits(acc[2][i][j][3] + bb) << 48);
        *(unsigned long long*)(vt + (size_t)n * SEQ + pos) = pk;
      }
    }
  }
}

// ---------------------------------------------------------------------------
// Wave-autonomous 64x64 GEMM core: ONE 64-lane wave per workgroup.
// Stages its own 64x32 A and B tiles (4 stage16 each), waits on its own vmcnt,
// 16 MFMA/iter. __syncthreads in a 1-wave group is a wave-local fence only —
// no cross-wave barrier coupling; TLP across workgroups hides the drains.
__device__ __forceinline__ void gemm_core_w64(
    const __hip_bfloat16* __restrict__ A,
    const __hip_bfloat16* __restrict__ B,
    int K, int m0, int n0, int ktiles,
    __hip_bfloat16* As /*64x32*/, __hip_bfloat16* Bs /*64x32*/,
    floatx4 acc[4][4])
{
  const int lane = threadIdx.x;     // 0..63
  const int quad = lane >> 4;
  const int r    = lane & 15;
  const int srow = lane >> 2;       // 0..15
  const int scol = (lane & 3) * 8;  // 0,8,16,24

  const __hip_bfloat16* aB = A + (size_t)(m0 + srow) * K + scol;
  const __hip_bfloat16* bB = B + (size_t)(n0 + srow) * K + scol;

  for (int kt = 0; kt < ktiles; ++kt) {
    const int k0 = kt * 32;
#pragma unroll
    for (int s = 0; s < 4; ++s) {
      stage16(aB + (size_t)s * 16 * K + k0, As + s * 512);
      stage16(bB + (size_t)s * 16 * K + k0, Bs + s * 512);
    }
    // vmcnt(0) only (exp/lgkm fields maxed — safe on both 4/6-bit lgkm encodings)
    __builtin_amdgcn_s_waitcnt(0x0F70);
    __syncthreads();   // 1-wave group: wave-local fence
    short8 a[4], b[4];
#pragma unroll
    for (int i = 0; i < 4; ++i) {
      a[i] = *(const short8*)(As + (i * 16 + r) * 32 + quad * 8);
      b[i] = *(const short8*)(Bs + (i * 16 + r) * 32 + quad * 8);
    }
#pragma unroll
    for (int i = 0; i < 4; ++i)
#pragma unroll
      for (int j = 0; j < 4; ++j)
        acc[i][j] = __builtin_amdgcn_mfma_f32_16x16x32_bf16(a[i], b[j], acc[i][j], 0, 0, 0);
    __syncthreads();   // drain ds_reads before next iter's stage16 overwrites
  }
}

// ---------------------------------------------------------------------------
// Scores: P'[z][q][k] = exp((Qb_z Kb_z^T)[q][k]/32) for k<=q (0 in the masked
// part of diagonal tiles), bf16; per-row partial sums atomicAdd'ed into lsum.
// Tiles fully above the diagonal skipped. 64x64 tiles, 1 wave per block.
// grid = (SEQ/64=32, SEQ/64=32, 4).
__global__ __launch_bounds__(64) void gemm_scores(
    const __hip_bfloat16* __restrict__ Qb, const __hip_bfloat16* __restrict__ Kb,
    __hip_bfloat16* __restrict__ Sb, float* __restrict__ lsum)
{
  const int z = blockIdx.z;
  const int m0 = blockIdx.y * 64, n0 = blockIdx.x * 64;
  if (n0 > m0) return;

  __shared__ __hip_bfloat16 As[64 * 32], Bs[64 * 32];
  const __hip_bfloat16* A = Qb + (size_t)z * SEQ * DMODEL;
  const __hip_bfloat16* B = Kb + (size_t)z * SEQ * DMODEL;
  __hip_bfloat16* outp = Sb + (size_t)z * SEQ * SEQ;
  floatx4 acc[4][4] = {};
  gemm_core_w64(A, B, DMODEL, m0, n0, DMODEL / 32, As, Bs, acc);

  const int lane = threadIdx.x;
  const int quad = lane >> 4, r = lane & 15;
  const float scale = 0.03125f;  // 1/sqrt(1024)
#pragma unroll
  for (int i = 0; i < 4; ++i) {
    const int mbase = m0 + i * 16 + quad * 4;
#pragma unroll
    for (int e = 0; e < 4; ++e) {
      const int row = mbase + e;
      float p = 0.f;
#pragma unroll
      for (int j = 0; j < 4; ++j) {
        const int n = n0 + j * 16 + r;
        const float pv = (n <= row) ? __expf(acc[i][j][e] * scale) : 0.f;
        outp[(size_t)row * SEQ + n] = __float2bfloat16(pv);
        p += pv;
      }
      // reduce over the 16 lanes of this quad
#pragma unroll
      for (int off = 1; off < 16; off <<= 1) p += __shfl_xor(p, off, 64);
      if (r == 0) atomicAdd(&lsum[z * SEQ + row], p);
    }
  }
}

// ---------------------------------------------------------------------------
// PV: Out[z][q][d] = (P'_z @ Vt_z^T)[q][d] / lsum[z*SEQ+q], fp32 out.
// 64x64 tiles, 1 wave per block; K truncated at the diagonal. m reversed so
// the longest-K blocks dispatch first. grid = (DMODEL/64=16, SEQ/64=32, 4).
__global__ __launch_bounds__(64) void gemm_pv(
    const __hip_bfloat16* __restrict__ Sb, const __hip_bfloat16* __restrict__ Vt,
    const float* __restrict__ lsum, float* __restrict__ Out)
{
  __shared__ __hip_bfloat16 As[64 * 32], Bs[64 * 32];
  const int z = blockIdx.z;
  const int mt = (int)gridDim.y - 1 - (int)blockIdx.y;   // longest-first
  const int m0 = mt * 64, n0 = blockIdx.x * 64;
  const __hip_bfloat16* A = Sb + (size_t)z * SEQ * SEQ;
  const __hip_bfloat16* B = Vt + (size_t)z * DMODEL * SEQ;
  float* outp = Out + (size_t)z * SEQ * DMODEL;

  floatx4 acc[4][4] = {};
  const int ktiles = (m0 + 64) / 32;  // causal truncation
  gemm_core_w64(A, B, SEQ, m0, n0, ktiles, As, Bs, acc);

  const int lane = threadIdx.x;
  const int quad = lane >> 4, r = lane & 15;
#pragma unroll
  for (int i = 0; i < 4; ++i) {
    const int mbase = m0 + i * 16 + quad * 4;
    float inv[4];
#pragma unroll
    for (int e = 0; e < 4; ++e) inv[e] = 1.f / lsum[z * SEQ + mbase + e];
#pragma unroll
    for (int j = 0; j < 4; ++j) {
      const int n = n0 + j * 16 + r;
#pragma unroll
      for (int e = 0; e < 4; ++e)
        outp[(size_t)(mbase + e) * DMODEL + n] = acc[i][j][e] * inv[e];
    }
  }
}

// ---------------------------------------------------------------------------
extern "C" void kernel_launch(void* const* d_in, const int* in_sizes, int n_in,
                              void* d_out, int out_size, void* d_ws, size_t ws_size,
                              hipStream_t stream)
{
  const float* X  = (const float*)d_in[0];
  const float* Wq = (const float*)d_in[1];
  const float* bq = (const float*)d_in[2];
  const float* Wk = (const float*)d_in[3];
  const float* bk = (const float*)d_in[4];
  const float* Wv = (const float*)d_in[5];
  const float* bv = (const float*)d_in[6];
  float* Out = (float*)d_out;

  // Workspace layout (~103 MB total)
  char* ws = (char*)d_ws;
  size_t off = 0;
  auto alloc = [&](size_t bytes) -> void* {
    void* p = ws + off;
    off += (bytes + 255) & ~(size_t)255;
    return p;
  };
  __hip_bfloat16* Xb  = (__hip_bfloat16*)alloc((size_t)MTOT * DMODEL * 2);    // 16 MB
  __hip_bfloat16* Wqb = (__hip_bfloat16*)alloc((size_t)DMODEL * DMODEL * 2);  // 2 MB
  __hip_bfloat16* Wkb = (__hip_bfloat16*)alloc((size_t)DMODEL * DMODEL * 2);
  __hip_bfloat16* Wvb = (__hip_bfloat16*)alloc((size_t)DMODEL * DMODEL * 2);
  __hip_bfloat16* Qb  = (__hip_bfloat16*)alloc((size_t)MTOT * DMODEL * 2);    // 16 MB
  __hip_bfloat16* Kb  = (__hip_bfloat16*)alloc((size_t)MTOT * DMODEL * 2);    // 16 MB
  __hip_bfloat16* Vt  = (__hip_bfloat16*)alloc((size_t)MTOT * DMODEL * 2);    // 16 MB
  __hip_bfloat16* Sb  = (__hip_bfloat16*)alloc((size_t)NBATCH * SEQ * SEQ * 2); // 32 MB
  float*          lsum = (float*)alloc((size_t)MTOT * 4);                     // 32 KB
  (void)ws_size; (void)in_sizes; (void)n_in; (void)out_size;

  // lsum must start at 0 (ws is re-poisoned to 0xAA before every launch)
  hipMemsetAsync(lsum, 0, (size_t)MTOT * 4, stream);
  // 1) converts (one kernel)
  convert_all<<<11264, 256, 0, stream>>>(X, Wq, Wk, Wv, Xb, Wqb, Wkb, Wvb);
  // 2) fused QKV projection (128x128); V written transposed
  gemm_qkv_fused<<<dim3(DMODEL / 128, MTOT / 128), 256, 0, stream>>>(
      Xb, Wqb, Wkb, Wvb, bq, bk, bv, Qb, Kb, Vt);
  // 3) scores: wave-autonomous 64x64 tiles, P' = exp(s) + atomic row sums
  gemm_scores<<<dim3(SEQ / 64, SEQ / 64, NBATCH), 64, 0, stream>>>(Qb, Kb, Sb, lsum);
  // 4) PV: wave-autonomous 64x64 tiles, epilogue normalization -> output
  gemm_pv<<<dim3(DMODEL / 64, SEQ / 64, NBATCH), 64, 0, stream>>>(Sb, Vt, lsum, Out);
}

// Round 8
// 282.817 us; speedup vs baseline: 1.0371x; 1.0371x over previous
//
#include <hip/hip_runtime.h>
#include <hip/hip_bf16.h>

// Self-attention: q=X@Wq.T+bq, k=..., v=...; S = causal_softmax(q k^T / 32); O = S v
// B=4, S=2048, D_IN=D_OUT=1024. fp32 in/out; internal compute bf16 MFMA + fp32 acc.
//
// R8 changes (R7's 1-wave cores reverted — a lone wave can't hide its own
// staging latency; measured 85 us, MfmaUtil 7.8%):
//  - scores & pv back to 4-wave 128x128 tiles but with BK=64: 32 MFMA/wave per
//    barrier (2x R4), barrier count halved, LDS 32 KB, acc stays 64 AGPR ->
//    __launch_bounds__(256,3) targets 3 blocks/CU (12 waves). Unlike m132's
//    BK=128 failure (64 KB LDS, occupancy drop), occupancy RISES here.
//  - LDS staged colchunk-major per 8-row stripe (lane i -> row i&7, colchunk
//    i>>3) so ds_read_b128 lane stride is 16 B (2-way bank aliasing = free),
//    avoiding the 16-way conflict of a naive [128][64] row-major tile.
//  - qkv kept at R4's 128x128 3-fused form (best measured: 65 us).
//
// MFMA fragment layouts (HW-verified per guide §3):
//  A: lane holds A[m=lane&15][k=(lane>>4)*8+j], j=0..7
//  B: lane holds B[k=(lane>>4)*8+j][n=lane&15]
//  C/D: lane holds D[row=(lane>>4)*4+e][col=lane&15], e=0..3

typedef __attribute__((ext_vector_type(8))) short short8;   // 8 bf16 = 4 VGPRs
typedef __attribute__((ext_vector_type(4))) float floatx4;  // MFMA acc

#define SEQ   2048
#define DMODEL 1024
#define NBATCH 4
#define MTOT  (SEQ * NBATCH)

// Direct global->LDS async copy, 16B per lane. LDS dst is wave-uniform base +
// lane*16 (per-lane scatter NOT supported).
__device__ __forceinline__ void stage16(const __hip_bfloat16* g, __hip_bfloat16* l)
{
  __builtin_amdgcn_global_load_lds(
      (const __attribute__((address_space(1))) void*)g,
      (__attribute__((address_space(3))) void*)l, 16, 0, 0);
}

__device__ __forceinline__ unsigned short bf16_bits(float f)
{
  __hip_bfloat16 h = __float2bfloat16(f);
  return *(unsigned short*)&h;
}

// ---------------------------------------------------------------------------
// One-kernel fp32 -> bf16 convert for all four inputs. Each block: 1024 elems.
__global__ __launch_bounds__(256) void convert_all(
    const float* __restrict__ X,  const float* __restrict__ Wq,
    const float* __restrict__ Wk, const float* __restrict__ Wv,
    __hip_bfloat16* __restrict__ Xb,  __hip_bfloat16* __restrict__ Wqb,
    __hip_bfloat16* __restrict__ Wkb, __hip_bfloat16* __restrict__ Wvb)
{
  const int b = blockIdx.x;
  const float* src; __hip_bfloat16* dst; int rel;
  if (b < 8192)       { src = X;  dst = Xb;  rel = b; }
  else if (b < 9216)  { src = Wq; dst = Wqb; rel = b - 8192; }
  else if (b < 10240) { src = Wk; dst = Wkb; rel = b - 9216; }
  else                { src = Wv; dst = Wvb; rel = b - 10240; }
  const int i = rel * 1024 + threadIdx.x * 4;
  float4 f = *(const float4*)(src + i);
  uint2 o;
  o.x = (unsigned)bf16_bits(f.x) | ((unsigned)bf16_bits(f.y) << 16);
  o.y = (unsigned)bf16_bits(f.z) | ((unsigned)bf16_bits(f.w) << 16);
  *(uint2*)(dst + i) = o;
}

// ---------------------------------------------------------------------------
// Fused QKV projection (R4 version, best measured). A-tile (X) staged once per
// k-iter, three 128x32 B-tiles; 48 MFMA/wave/barrier. Q,K row-major; V -> Vt.
// grid = (8, 64), 256 threads, 32 KB LDS.
__global__ __launch_bounds__(256, 2) void gemm_qkv_fused(
    const __hip_bfloat16* __restrict__ Xb,
    const __hip_bfloat16* __restrict__ Wqb,
    const __hip_bfloat16* __restrict__ Wkb,
    const __hip_bfloat16* __restrict__ Wvb,
    const float* __restrict__ bq, const float* __restrict__ bk, const float* __restrict__ bv,
    __hip_bfloat16* __restrict__ Qb, __hip_bfloat16* __restrict__ Kb, __hip_bfloat16* __restrict__ Vt)
{
  __shared__ __hip_bfloat16 As[128 * 32];
  __shared__ __hip_bfloat16 Bs[3][128 * 32];
  const int m0 = blockIdx.y * 128, n0 = blockIdx.x * 128;
  const int tid  = threadIdx.x;
  const int lane = tid & 63;
  const int wave = tid >> 6;
  const int quad = lane >> 4;
  const int r    = lane & 15;
  const int wm   = (wave >> 1) * 64;
  const int wn   = (wave & 1) * 64;
  const int srow = wave * 16 + (lane >> 2);   // 0..63
  const int scol = (lane & 3) * 8;            // 0,8,16,24

  const __hip_bfloat16* Wp[3] = {Wqb, Wkb, Wvb};

  __hip_bfloat16* lA0 = As + wave * 512;
  __hip_bfloat16* lA1 = As + 2048 + wave * 512;

  const __hip_bfloat16* aR0 = Xb + (size_t)(m0 + srow) * DMODEL + scol;
  const __hip_bfloat16* aR1 = aR0 + (size_t)64 * DMODEL;

  floatx4 acc[3][4][4] = {};

  for (int kt = 0; kt < DMODEL / 32; ++kt) {
    const int k0 = kt * 32;
    stage16(aR0 + k0, lA0);
    stage16(aR1 + k0, lA1);
#pragma unroll
    for (int w = 0; w < 3; ++w) {
      stage16(Wp[w] + (size_t)(n0 + srow) * DMODEL + scol + k0,      Bs[w] + wave * 512);
      stage16(Wp[w] + (size_t)(n0 + 64 + srow) * DMODEL + scol + k0, Bs[w] + 2048 + wave * 512);
    }
    __syncthreads();
    short8 a[4];
#pragma unroll
    for (int i = 0; i < 4; ++i)
      a[i] = *(const short8*)(As + (wm + i * 16 + r) * 32 + quad * 8);
#pragma unroll
    for (int w = 0; w < 3; ++w) {
      short8 b[4];
#pragma unroll
      for (int j = 0; j < 4; ++j)
        b[j] = *(const short8*)(Bs[w] + (wn + j * 16 + r) * 32 + quad * 8);
#pragma unroll
      for (int i = 0; i < 4; ++i)
#pragma unroll
        for (int j = 0; j < 4; ++j)
          acc[w][i][j] = __builtin_amdgcn_mfma_f32_16x16x32_bf16(a[i], b[j], acc[w][i][j], 0, 0, 0);
    }
    __syncthreads();
  }

  // Q, K: row-major stores
  {
    __hip_bfloat16* Op[2] = {Qb, Kb};
    const float* Bp[2] = {bq, bk};
#pragma unroll
    for (int w = 0; w < 2; ++w) {
      __hip_bfloat16* out = Op[w];
#pragma unroll
      for (int j = 0; j < 4; ++j) {
        const int n = n0 + wn + j * 16 + r;
        const float bb = Bp[w][n];
#pragma unroll
        for (int i = 0; i < 4; ++i) {
          const int mbase = m0 + wm + i * 16 + quad * 4;
#pragma unroll
          for (int e = 0; e < 4; ++e)
            out[(size_t)(mbase + e) * DMODEL + n] = __float2bfloat16(acc[w][i][j][e] + bb);
        }
      }
    }
  }
  // V: transposed store Vt[z][d=n][pos], 8B packed per (i,j). z = batch of m0.
  {
    const int z    = m0 >> 11;           // SEQ = 2048
    const int posb = (m0 & (SEQ - 1)) + wm;
    __hip_bfloat16* vt = Vt + (size_t)z * DMODEL * SEQ;
#pragma unroll
    for (int j = 0; j < 4; ++j) {
      const int n = n0 + wn + j * 16 + r;
      const float bb = bv[n];
#pragma unroll
      for (int i = 0; i < 4; ++i) {
        const int pos = posb + i * 16 + quad * 4;
        unsigned long long pk =
            (unsigned long long)bf16_bits(acc[2][i][j][0] + bb)
          | ((unsigned long long)bf16_bits(acc[2][i][j][1] + bb) << 16)
          | ((unsigned long long)bf16_bits(acc[2][i][j][2] + bb) << 32)
          | ((unsigned long long)bf16_bits(acc[2][i][j][3] + bb) << 48);
        *(unsigned long long*)(vt + (size_t)n * SEQ + pos) = pk;
      }
    }
  }
}

// ---------------------------------------------------------------------------
// BK=64 GEMM core: C[128x128] += A * B^T, A/B bf16 row-major [.,K].
// 4 waves; wave w stages rows [32w,32w+32) of both tiles in 4 stripes of 8
// rows. Within a stripe, lane i covers row (i&7), colchunk (i>>3) — LDS is
// colchunk-major per stripe, so ds_read_b128 lanes are 16 B apart (2-way
// bank aliasing, free). 32 MFMA/wave per barrier.
// LDS addr of A[m][k] (elems): (m>>5)*2048 + ((m>>3)&3)*512 + (k>>3)*64 + (m&7)*8 + (k&7)
__device__ __forceinline__ void gemm_core_bk64(
    const __hip_bfloat16* __restrict__ A,
    const __hip_bfloat16* __restrict__ B,
    int K, int m0, int n0, int kchunks,
    __hip_bfloat16* As /*128x64*/, __hip_bfloat16* Bs /*128x64*/,
    floatx4 acc[4][4])
{
  const int tid  = threadIdx.x;
  const int lane = tid & 63;
  const int wave = tid >> 6;
  const int quad = lane >> 4;
  const int r    = lane & 15;
  const int wm   = (wave >> 1) * 64;
  const int wn   = (wave & 1) * 64;
  const int g_row = wave * 32 + (lane & 7);   // +8s per stripe
  const int g_col = (lane >> 3) * 8;          // 0..56

  const __hip_bfloat16* aB = A + (size_t)(m0 + g_row) * K + g_col;
  const __hip_bfloat16* bB = B + (size_t)(n0 + g_row) * K + g_col;
  __hip_bfloat16* lA = As + wave * 2048;
  __hip_bfloat16* lB = Bs + wave * 2048;

  for (int kt = 0; kt < kchunks; ++kt) {
    const int k0 = kt * 64;
#pragma unroll
    for (int s = 0; s < 4; ++s) {
      stage16(aB + (size_t)(8 * s) * K + k0, lA + s * 512);
      stage16(bB + (size_t)(8 * s) * K + k0, lB + s * 512);
    }
    __syncthreads();
#pragma unroll
    for (int kk = 0; kk < 2; ++kk) {
      short8 a[4], b[4];
#pragma unroll
      for (int i = 0; i < 4; ++i) {
        const int ma = wm + i * 16 + r;
        const int nb = wn + i * 16 + r;
        const int kc = kk * 4 + quad;   // colchunk of k = kk*32 + quad*8
        a[i] = *(const short8*)(As + (ma >> 5) * 2048 + ((ma >> 3) & 3) * 512 + kc * 64 + (ma & 7) * 8);
        b[i] = *(const short8*)(Bs + (nb >> 5) * 2048 + ((nb >> 3) & 3) * 512 + kc * 64 + (nb & 7) * 8);
      }
#pragma unroll
      for (int i = 0; i < 4; ++i)
#pragma unroll
        for (int j = 0; j < 4; ++j)
          acc[i][j] = __builtin_amdgcn_mfma_f32_16x16x32_bf16(a[i], b[j], acc[i][j], 0, 0, 0);
    }
    __syncthreads();
  }
}

// ---------------------------------------------------------------------------
// Scores: P'[z][q][k] = exp((Qb_z Kb_z^T)[q][k]/32) for k<=q (0 in the masked
// part of diagonal tiles), bf16; per-row partial sums atomicAdd'ed into lsum.
// Tiles fully above the diagonal skipped. 128x128 tiles, BK=64, 3 blocks/CU.
// grid = (16,16,4).
__global__ __launch_bounds__(256, 3) void gemm_scores(
    const __hip_bfloat16* __restrict__ Qb, const __hip_bfloat16* __restrict__ Kb,
    __hip_bfloat16* __restrict__ Sb, float* __restrict__ lsum)
{
  const int z = blockIdx.z;
  const int m0 = blockIdx.y * 128, n0 = blockIdx.x * 128;
  if (n0 > m0) return;

  __shared__ __hip_bfloat16 As[128 * 64], Bs[128 * 64];
  const __hip_bfloat16* A = Qb + (size_t)z * SEQ * DMODEL;
  const __hip_bfloat16* B = Kb + (size_t)z * SEQ * DMODEL;
  __hip_bfloat16* outp = Sb + (size_t)z * SEQ * SEQ;
  floatx4 acc[4][4] = {};
  gemm_core_bk64(A, B, DMODEL, m0, n0, DMODEL / 64, As, Bs, acc);

  const int lane = threadIdx.x & 63, wave = threadIdx.x >> 6;
  const int quad = lane >> 4, r = lane & 15;
  const int wm = (wave >> 1) * 64, wn = (wave & 1) * 64;
  const float scale = 0.03125f;  // 1/sqrt(1024)
#pragma unroll
  for (int i = 0; i < 4; ++i) {
    const int mbase = m0 + wm + i * 16 + quad * 4;
#pragma unroll
    for (int e = 0; e < 4; ++e) {
      const int row = mbase + e;
      float p = 0.f;
#pragma unroll
      for (int j = 0; j < 4; ++j) {
        const int n = n0 + wn + j * 16 + r;
        const float pv = (n <= row) ? __expf(acc[i][j][e] * scale) : 0.f;
        outp[(size_t)row * SEQ + n] = __float2bfloat16(pv);
        p += pv;
      }
#pragma unroll
      for (int off = 1; off < 16; off <<= 1) p += __shfl_xor(p, off, 64);
      if (r == 0) atomicAdd(&lsum[z * SEQ + row], p);
    }
  }
}

// ---------------------------------------------------------------------------
// PV: Out[z][q][d] = (P'_z @ Vt_z^T)[q][d] / lsum[z*SEQ+q], fp32 out.
// 128x128 tiles, BK=64, K truncated at the diagonal. grid = (8,16,4).
__global__ __launch_bounds__(256, 3) void gemm_pv(
    const __hip_bfloat16* __restrict__ Sb, const __hip_bfloat16* __restrict__ Vt,
    const float* __restrict__ lsum, float* __restrict__ Out)
{
  __shared__ __hip_bfloat16 As[128 * 64], Bs[128 * 64];
  const int z = blockIdx.z;
  const int m0 = blockIdx.y * 128, n0 = blockIdx.x * 128;
  const __hip_bfloat16* A = Sb + (size_t)z * SEQ * SEQ;
  const __hip_bfloat16* B = Vt + (size_t)z * DMODEL * SEQ;
  float* outp = Out + (size_t)z * SEQ * DMODEL;

  floatx4 acc[4][4] = {};
  const int kchunks = (m0 + 128) / 64;  // causal truncation
  gemm_core_bk64(A, B, SEQ, m0, n0, kchunks, As, Bs, acc);

  const int lane = threadIdx.x & 63, wave = threadIdx.x >> 6;
  const int quad = lane >> 4, r = lane & 15;
  const int wm = (wave >> 1) * 64, wn = (wave & 1) * 64;
#pragma unroll
  for (int i = 0; i < 4; ++i) {
    const int mbase = m0 + wm + i * 16 + quad * 4;
    float inv[4];
#pragma unroll
    for (int e = 0; e < 4; ++e) inv[e] = 1.f / lsum[z * SEQ + mbase + e];
#pragma unroll
    for (int j = 0; j < 4; ++j) {
      const int n = n0 + wn + j * 16 + r;
#pragma unroll
      for (int e = 0; e < 4; ++e)
        outp[(size_t)(mbase + e) * DMODEL + n] = acc[i][j][e] * inv[e];
    }
  }
}

// ---------------------------------------------------------------------------
extern "C" void kernel_launch(void* const* d_in, const int* in_sizes, int n_in,
                              void* d_out, int out_size, void* d_ws, size_t ws_size,
                              hipStream_t stream)
{
  const float* X  = (const float*)d_in[0];
  const float* Wq = (const float*)d_in[1];
  const float* bq = (const float*)d_in[2];
  const float* Wk = (const float*)d_in[3];
  const float* bk = (const float*)d_in[4];
  const float* Wv = (const float*)d_in[5];
  const float* bv = (const float*)d_in[6];
  float* Out = (float*)d_out;

  // Workspace layout (~103 MB total)
  char* ws = (char*)d_ws;
  size_t off = 0;
  auto alloc = [&](size_t bytes) -> void* {
    void* p = ws + off;
    off += (bytes + 255) & ~(size_t)255;
    return p;
  };
  __hip_bfloat16* Xb  = (__hip_bfloat16*)alloc((size_t)MTOT * DMODEL * 2);    // 16 MB
  __hip_bfloat16* Wqb = (__hip_bfloat16*)alloc((size_t)DMODEL * DMODEL * 2);  // 2 MB
  __hip_bfloat16* Wkb = (__hip_bfloat16*)alloc((size_t)DMODEL * DMODEL * 2);
  __hip_bfloat16* Wvb = (__hip_bfloat16*)alloc((size_t)DMODEL * DMODEL * 2);
  __hip_bfloat16* Qb  = (__hip_bfloat16*)alloc((size_t)MTOT * DMODEL * 2);    // 16 MB
  __hip_bfloat16* Kb  = (__hip_bfloat16*)alloc((size_t)MTOT * DMODEL * 2);    // 16 MB
  __hip_bfloat16* Vt  = (__hip_bfloat16*)alloc((size_t)MTOT * DMODEL * 2);    // 16 MB
  __hip_bfloat16* Sb  = (__hip_bfloat16*)alloc((size_t)NBATCH * SEQ * SEQ * 2); // 32 MB
  float*          lsum = (float*)alloc((size_t)MTOT * 4);                     // 32 KB
  (void)ws_size; (void)in_sizes; (void)n_in; (void)out_size;

  // lsum must start at 0 (ws is re-poisoned to 0xAA before every launch)
  hipMemsetAsync(lsum, 0, (size_t)MTOT * 4, stream);
  // 1) converts (one kernel)
  convert_all<<<11264, 256, 0, stream>>>(X, Wq, Wk, Wv, Xb, Wqb, Wkb, Wvb);
  // 2) fused QKV projection (128x128); V written transposed
  gemm_qkv_fused<<<dim3(DMODEL / 128, MTOT / 128), 256, 0, stream>>>(
      Xb, Wqb, Wkb, Wvb, bq, bk, bv, Qb, Kb, Vt);
  // 3) scores: BK=64 cores, P' = exp(s) + atomic row sums
  gemm_scores<<<dim3(SEQ / 128, SEQ / 128, NBATCH), 256, 0, stream>>>(Qb, Kb, Sb, lsum);
  // 4) PV: BK=64 cores, epilogue normalization -> output
  gemm_pv<<<dim3(DMODEL / 128, SEQ / 128, NBATCH), 256, 0, stream>>>(Sb, Vt, lsum, Out);
}

// Round 9
// 254.249 us; speedup vs baseline: 1.1536x; 1.1124x over previous
//
#include <hip/hip_runtime.h>
#include <hip/hip_bf16.h>

// Self-attention: q=X@Wq.T+bq, k=..., v=...; S = causal_softmax(q k^T / 32); O = S v
// B=4, S=2048, D_IN=D_OUT=1024. fp32 in/out; internal compute bf16 MFMA + fp32 acc.
//
// R9 change: attention GEMMs rebuilt for CONCURRENCY. Evidence: the same
// BK=32 core ran 686 TF at grid 1536 uniform blocks (R2 qkv) but ~260 TF at
// grid 544/512 with dummies/imbalance (R4..R8 scores/pv, occ 18%, MfmaUtil 9%)
// — block count is the dominant variable, resources were never the limit.
//  - scores: 64m x 128n tiles, 2-wave blocks, BK=32, COMPACT grid (1088 real
//    blocks via linear-id decode; no dummy early-exit blocks). 12 KB LDS,
//    64 AGPR -> ~8 schedulable blocks/CU.
//  - pv: same 2-wave core, 1024 blocks, longest-K-first, diagonal-truncated K.
//  - qkv/convert unchanged (R4 forms, qkv = 780 TF best measured).
//
// MFMA fragment layouts (HW-verified per guide §3):
//  A: lane holds A[m=lane&15][k=(lane>>4)*8+j], j=0..7
//  B: lane holds B[k=(lane>>4)*8+j][n=lane&15]
//  C/D: lane holds D[row=(lane>>4)*4+e][col=lane&15], e=0..3

typedef __attribute__((ext_vector_type(8))) short short8;   // 8 bf16 = 4 VGPRs
typedef __attribute__((ext_vector_type(4))) float floatx4;  // MFMA acc

#define SEQ   2048
#define DMODEL 1024
#define NBATCH 4
#define MTOT  (SEQ * NBATCH)

// Direct global->LDS async copy, 16B per lane. LDS dst is wave-uniform base +
// lane*16 (per-lane scatter NOT supported).
__device__ __forceinline__ void stage16(const __hip_bfloat16* g, __hip_bfloat16* l)
{
  __builtin_amdgcn_global_load_lds(
      (const __attribute__((address_space(1))) void*)g,
      (__attribute__((address_space(3))) void*)l, 16, 0, 0);
}

__device__ __forceinline__ unsigned short bf16_bits(float f)
{
  __hip_bfloat16 h = __float2bfloat16(f);
  return *(unsigned short*)&h;
}

// ---------------------------------------------------------------------------
// One-kernel fp32 -> bf16 convert for all four inputs. Each block: 1024 elems.
__global__ __launch_bounds__(256) void convert_all(
    const float* __restrict__ X,  const float* __restrict__ Wq,
    const float* __restrict__ Wk, const float* __restrict__ Wv,
    __hip_bfloat16* __restrict__ Xb,  __hip_bfloat16* __restrict__ Wqb,
    __hip_bfloat16* __restrict__ Wkb, __hip_bfloat16* __restrict__ Wvb)
{
  const int b = blockIdx.x;
  const float* src; __hip_bfloat16* dst; int rel;
  if (b < 8192)       { src = X;  dst = Xb;  rel = b; }
  else if (b < 9216)  { src = Wq; dst = Wqb; rel = b - 8192; }
  else if (b < 10240) { src = Wk; dst = Wkb; rel = b - 9216; }
  else                { src = Wv; dst = Wvb; rel = b - 10240; }
  const int i = rel * 1024 + threadIdx.x * 4;
  float4 f = *(const float4*)(src + i);
  uint2 o;
  o.x = (unsigned)bf16_bits(f.x) | ((unsigned)bf16_bits(f.y) << 16);
  o.y = (unsigned)bf16_bits(f.z) | ((unsigned)bf16_bits(f.w) << 16);
  *(uint2*)(dst + i) = o;
}

// ---------------------------------------------------------------------------
// Fused QKV projection (R4 version, best measured). A-tile (X) staged once per
// k-iter, three 128x32 B-tiles; 48 MFMA/wave/barrier. Q,K row-major; V -> Vt.
// grid = (8, 64), 256 threads, 32 KB LDS.
__global__ __launch_bounds__(256, 2) void gemm_qkv_fused(
    const __hip_bfloat16* __restrict__ Xb,
    const __hip_bfloat16* __restrict__ Wqb,
    const __hip_bfloat16* __restrict__ Wkb,
    const __hip_bfloat16* __restrict__ Wvb,
    const float* __restrict__ bq, const float* __restrict__ bk, const float* __restrict__ bv,
    __hip_bfloat16* __restrict__ Qb, __hip_bfloat16* __restrict__ Kb, __hip_bfloat16* __restrict__ Vt)
{
  __shared__ __hip_bfloat16 As[128 * 32];
  __shared__ __hip_bfloat16 Bs[3][128 * 32];
  const int m0 = blockIdx.y * 128, n0 = blockIdx.x * 128;
  const int tid  = threadIdx.x;
  const int lane = tid & 63;
  const int wave = tid >> 6;
  const int quad = lane >> 4;
  const int r    = lane & 15;
  const int wm   = (wave >> 1) * 64;
  const int wn   = (wave & 1) * 64;
  const int srow = wave * 16 + (lane >> 2);   // 0..63
  const int scol = (lane & 3) * 8;            // 0,8,16,24

  const __hip_bfloat16* Wp[3] = {Wqb, Wkb, Wvb};

  __hip_bfloat16* lA0 = As + wave * 512;
  __hip_bfloat16* lA1 = As + 2048 + wave * 512;

  const __hip_bfloat16* aR0 = Xb + (size_t)(m0 + srow) * DMODEL + scol;
  const __hip_bfloat16* aR1 = aR0 + (size_t)64 * DMODEL;

  floatx4 acc[3][4][4] = {};

  for (int kt = 0; kt < DMODEL / 32; ++kt) {
    const int k0 = kt * 32;
    stage16(aR0 + k0, lA0);
    stage16(aR1 + k0, lA1);
#pragma unroll
    for (int w = 0; w < 3; ++w) {
      stage16(Wp[w] + (size_t)(n0 + srow) * DMODEL + scol + k0,      Bs[w] + wave * 512);
      stage16(Wp[w] + (size_t)(n0 + 64 + srow) * DMODEL + scol + k0, Bs[w] + 2048 + wave * 512);
    }
    __syncthreads();
    short8 a[4];
#pragma unroll
    for (int i = 0; i < 4; ++i)
      a[i] = *(const short8*)(As + (wm + i * 16 + r) * 32 + quad * 8);
#pragma unroll
    for (int w = 0; w < 3; ++w) {
      short8 b[4];
#pragma unroll
      for (int j = 0; j < 4; ++j)
        b[j] = *(const short8*)(Bs[w] + (wn + j * 16 + r) * 32 + quad * 8);
#pragma unroll
      for (int i = 0; i < 4; ++i)
#pragma unroll
        for (int j = 0; j < 4; ++j)
          acc[w][i][j] = __builtin_amdgcn_mfma_f32_16x16x32_bf16(a[i], b[j], acc[w][i][j], 0, 0, 0);
    }
    __syncthreads();
  }

  // Q, K: row-major stores
  {
    __hip_bfloat16* Op[2] = {Qb, Kb};
    const float* Bp[2] = {bq, bk};
#pragma unroll
    for (int w = 0; w < 2; ++w) {
      __hip_bfloat16* out = Op[w];
#pragma unroll
      for (int j = 0; j < 4; ++j) {
        const int n = n0 + wn + j * 16 + r;
        const float bb = Bp[w][n];
#pragma unroll
        for (int i = 0; i < 4; ++i) {
          const int mbase = m0 + wm + i * 16 + quad * 4;
#pragma unroll
          for (int e = 0; e < 4; ++e)
            out[(size_t)(mbase + e) * DMODEL + n] = __float2bfloat16(acc[w][i][j][e] + bb);
        }
      }
    }
  }
  // V: transposed store Vt[z][d=n][pos], 8B packed per (i,j). z = batch of m0.
  {
    const int z    = m0 >> 11;           // SEQ = 2048
    const int posb = (m0 & (SEQ - 1)) + wm;
    __hip_bfloat16* vt = Vt + (size_t)z * DMODEL * SEQ;
#pragma unroll
    for (int j = 0; j < 4; ++j) {
      const int n = n0 + wn + j * 16 + r;
      const float bb = bv[n];
#pragma unroll
      for (int i = 0; i < 4; ++i) {
        const int pos = posb + i * 16 + quad * 4;
        unsigned long long pk =
            (unsigned long long)bf16_bits(acc[2][i][j][0] + bb)
          | ((unsigned long long)bf16_bits(acc[2][i][j][1] + bb) << 16)
          | ((unsigned long long)bf16_bits(acc[2][i][j][2] + bb) << 32)
          | ((unsigned long long)bf16_bits(acc[2][i][j][3] + bb) << 48);
        *(unsigned long long*)(vt + (size_t)n * SEQ + pos) = pk;
      }
    }
  }
}

// ---------------------------------------------------------------------------
// 2-wave GEMM core: C[64x128] += A * B^T, A/B bf16 row-major [.,K], BK=32.
// 128 threads = 2 waves; wave w owns n-half wn = w*64 (acc [4][4] = 64 AGPR).
// Staging per iter: A 64x32 (wave w: 16-row chunks {2w, 2w+1}), B 128x32
// (wave w: chunks {4w..4w+3}); 6 stage16/thread. LDS layout row-major [.,32]
// (identical ds_read pattern to the R4 core: 2-way bank aliasing, free).
__device__ __forceinline__ void gemm_core_2w(
    const __hip_bfloat16* __restrict__ A,
    const __hip_bfloat16* __restrict__ B,
    int K, int m0, int n0, int kchunks,
    __hip_bfloat16* As /*64x32*/, __hip_bfloat16* Bs /*128x32*/,
    floatx4 acc[4][4])
{
  const int tid  = threadIdx.x;
  const int lane = tid & 63;
  const int wave = tid >> 6;          // 0..1
  const int quad = lane >> 4;
  const int r    = lane & 15;
  const int wn   = wave * 64;
  const int lrow = lane >> 2;         // 0..15
  const int lcol = (lane & 3) * 8;    // 0,8,16,24

  const __hip_bfloat16* aB = A + (size_t)(m0 + wave * 32 + lrow) * K + lcol;
  const __hip_bfloat16* bB = B + (size_t)(n0 + wave * 64 + lrow) * K + lcol;
  __hip_bfloat16* lA = As + wave * 1024;   // 2 chunks of 512
  __hip_bfloat16* lB = Bs + wave * 2048;   // 4 chunks of 512

  for (int kt = 0; kt < kchunks; ++kt) {
    const int k0 = kt * 32;
#pragma unroll
    for (int s = 0; s < 2; ++s)
      stage16(aB + (size_t)(16 * s) * K + k0, lA + s * 512);
#pragma unroll
    for (int s = 0; s < 4; ++s)
      stage16(bB + (size_t)(16 * s) * K + k0, lB + s * 512);
    __syncthreads();
    short8 a[4], b[4];
#pragma unroll
    for (int i = 0; i < 4; ++i) {
      a[i] = *(const short8*)(As + (i * 16 + r) * 32 + quad * 8);
      b[i] = *(const short8*)(Bs + (wn + i * 16 + r) * 32 + quad * 8);
    }
#pragma unroll
    for (int i = 0; i < 4; ++i)
#pragma unroll
      for (int j = 0; j < 4; ++j)
        acc[i][j] = __builtin_amdgcn_mfma_f32_16x16x32_bf16(a[i], b[j], acc[i][j], 0, 0, 0);
    __syncthreads();
  }
}

// ---------------------------------------------------------------------------
// Scores: P'[z][q][k] = exp((Qb_z Kb_z^T)[q][k]/32) for k<=q (0 in the masked
// part of diagonal tiles), bf16; per-row sums atomicAdd'ed into lsum.
// 64m x 128n tiles, 2-wave blocks, COMPACT grid: blockIdx.x = linear id over
// the 272 active (mt,nt) pairs per batch. Pair p (mt=2p,2p+1) contributes
// 2(p+1) blocks; cumulative p(p+1). grid = (272, NBATCH), 128 threads.
__global__ __launch_bounds__(128, 4) void gemm_scores(
    const __hip_bfloat16* __restrict__ Qb, const __hip_bfloat16* __restrict__ Kb,
    __hip_bfloat16* __restrict__ Sb, float* __restrict__ lsum)
{
  const int z = blockIdx.y;
  const int L = blockIdx.x;
  // decode pair index p: largest p with p(p+1) <= L
  int p = (int)((sqrtf(4.0f * (float)L + 1.0f) - 1.0f) * 0.5f);
  while ((p + 1) * (p + 2) <= L) ++p;
  while (p * (p + 1) > L) --p;
  const int o  = L - p * (p + 1);          // 0 .. 2p+1
  const int mt = 2 * p + (o > p ? 1 : 0);
  const int nt = (o > p) ? (o - p - 1) : o;
  const int m0 = mt * 64, n0 = nt * 128;

  __shared__ __hip_bfloat16 As[64 * 32], Bs[128 * 32];
  const __hip_bfloat16* A = Qb + (size_t)z * SEQ * DMODEL;
  const __hip_bfloat16* B = Kb + (size_t)z * SEQ * DMODEL;
  __hip_bfloat16* outp = Sb + (size_t)z * SEQ * SEQ;
  floatx4 acc[4][4] = {};
  gemm_core_2w(A, B, DMODEL, m0, n0, DMODEL / 32, As, Bs, acc);

  const int lane = threadIdx.x & 63, wave = threadIdx.x >> 6;
  const int quad = lane >> 4, r = lane & 15;
  const int wn = wave * 64;
  const float scale = 0.03125f;  // 1/sqrt(1024)
#pragma unroll
  for (int i = 0; i < 4; ++i) {
    const int mbase = m0 + i * 16 + quad * 4;
#pragma unroll
    for (int e = 0; e < 4; ++e) {
      const int row = mbase + e;
      float psum = 0.f;
#pragma unroll
      for (int j = 0; j < 4; ++j) {
        const int n = n0 + wn + j * 16 + r;
        const float pv = (n <= row) ? __expf(acc[i][j][e] * scale) : 0.f;
        outp[(size_t)row * SEQ + n] = __float2bfloat16(pv);
        psum += pv;
      }
#pragma unroll
      for (int off = 1; off < 16; off <<= 1) psum += __shfl_xor(psum, off, 64);
      if (r == 0) atomicAdd(&lsum[z * SEQ + row], psum);
    }
  }
}

// ---------------------------------------------------------------------------
// PV: Out[z][q][d] = (P'_z @ Vt_z^T)[q][d] / lsum[z*SEQ+q], fp32 out.
// 64m x 128n tiles, 2-wave blocks; K truncated at the diagonal; longest-K
// blocks dispatched first. grid = (DMODEL/128=8, SEQ/64=32, 4), 128 threads.
__global__ __launch_bounds__(128, 4) void gemm_pv(
    const __hip_bfloat16* __restrict__ Sb, const __hip_bfloat16* __restrict__ Vt,
    const float* __restrict__ lsum, float* __restrict__ Out)
{
  __shared__ __hip_bfloat16 As[64 * 32], Bs[128 * 32];
  const int z = blockIdx.z;
  const int mt = (int)gridDim.y - 1 - (int)blockIdx.y;  // longest-first
  const int m0 = mt * 64, n0 = blockIdx.x * 128;
  const __hip_bfloat16* A = Sb + (size_t)z * SEQ * SEQ;
  const __hip_bfloat16* B = Vt + (size_t)z * DMODEL * SEQ;
  float* outp = Out + (size_t)z * SEQ * DMODEL;

  floatx4 acc[4][4] = {};
  const int kchunks = 2 * mt + 2;   // (m0+64)/32: causal truncation
  gemm_core_2w(A, B, SEQ, m0, n0, kchunks, As, Bs, acc);

  const int lane = threadIdx.x & 63, wave = threadIdx.x >> 6;
  const int quad = lane >> 4, r = lane & 15;
  const int wn = wave * 64;
#pragma unroll
  for (int i = 0; i < 4; ++i) {
    const int mbase = m0 + i * 16 + quad * 4;
    float inv[4];
#pragma unroll
    for (int e = 0; e < 4; ++e) inv[e] = 1.f / lsum[z * SEQ + mbase + e];
#pragma unroll
    for (int j = 0; j < 4; ++j) {
      const int n = n0 + wn + j * 16 + r;
#pragma unroll
      for (int e = 0; e < 4; ++e)
        outp[(size_t)(mbase + e) * DMODEL + n] = acc[i][j][e] * inv[e];
    }
  }
}

// ---------------------------------------------------------------------------
extern "C" void kernel_launch(void* const* d_in, const int* in_sizes, int n_in,
                              void* d_out, int out_size, void* d_ws, size_t ws_size,
                              hipStream_t stream)
{
  const float* X  = (const float*)d_in[0];
  const float* Wq = (const float*)d_in[1];
  const float* bq = (const float*)d_in[2];
  const float* Wk = (const float*)d_in[3];
  const float* bk = (const float*)d_in[4];
  const float* Wv = (const float*)d_in[5];
  const float* bv = (const float*)d_in[6];
  float* Out = (float*)d_out;

  // Workspace layout (~103 MB total)
  char* ws = (char*)d_ws;
  size_t off = 0;
  auto alloc = [&](size_t bytes) -> void* {
    void* p = ws + off;
    off += (bytes + 255) & ~(size_t)255;
    return p;
  };
  __hip_bfloat16* Xb  = (__hip_bfloat16*)alloc((size_t)MTOT * DMODEL * 2);    // 16 MB
  __hip_bfloat16* Wqb = (__hip_bfloat16*)alloc((size_t)DMODEL * DMODEL * 2);  // 2 MB
  __hip_bfloat16* Wkb = (__hip_bfloat16*)alloc((size_t)DMODEL * DMODEL * 2);
  __hip_bfloat16* Wvb = (__hip_bfloat16*)alloc((size_t)DMODEL * DMODEL * 2);
  __hip_bfloat16* Qb  = (__hip_bfloat16*)alloc((size_t)MTOT * DMODEL * 2);    // 16 MB
  __hip_bfloat16* Kb  = (__hip_bfloat16*)alloc((size_t)MTOT * DMODEL * 2);    // 16 MB
  __hip_bfloat16* Vt  = (__hip_bfloat16*)alloc((size_t)MTOT * DMODEL * 2);    // 16 MB
  __hip_bfloat16* Sb  = (__hip_bfloat16*)alloc((size_t)NBATCH * SEQ * SEQ * 2); // 32 MB
  float*          lsum = (float*)alloc((size_t)MTOT * 4);                     // 32 KB
  (void)ws_size; (void)in_sizes; (void)n_in; (void)out_size;

  // lsum must start at 0 (ws is re-poisoned to 0xAA before every launch)
  hipMemsetAsync(lsum, 0, (size_t)MTOT * 4, stream);
  // 1) converts (one kernel)
  convert_all<<<11264, 256, 0, stream>>>(X, Wq, Wk, Wv, Xb, Wqb, Wkb, Wvb);
  // 2) fused QKV projection (128x128); V written transposed
  gemm_qkv_fused<<<dim3(DMODEL / 128, MTOT / 128), 256, 0, stream>>>(
      Xb, Wqb, Wkb, Wvb, bq, bk, bv, Qb, Kb, Vt);
  // 3) scores: 2-wave 64x128 tiles, compact grid, P' = exp(s) + atomic row sums
  gemm_scores<<<dim3(272, NBATCH), 128, 0, stream>>>(Qb, Kb, Sb, lsum);
  // 4) PV: 2-wave 64x128 tiles, longest-first, epilogue normalization
  gemm_pv<<<dim3(DMODEL / 128, SEQ / 64, NBATCH), 128, 0, stream>>>(Sb, Vt, lsum, Out);
}

// Round 10
// 248.151 us; speedup vs baseline: 1.1819x; 1.0246x over previous
//
#include <hip/hip_runtime.h>
#include <hip/hip_bf16.h>

// Self-attention: q=X@Wq.T+bq, k=..., v=...; S = causal_softmax(q k^T / 32); O = S v
// B=4, S=2048, D_IN=D_OUT=1024. fp32 in/out; internal compute bf16 MFMA + fp32 acc.
//
// R10 changes (consolidation on the R9 win):
//  - lsum machinery ELIMINATED. pv computes row sums itself via an extra MFMA
//    per k-iter against an all-ones B-fragment: acc_s[i] = mfma(a[i], 1, acc_s[i])
//    accumulates sum_k P'[m][k] in fp32 directly in C-layout (every column of
//    acc_s holds the row sum -> inv = 1/acc_s[i][e], no cross-lane traffic).
//    Sums exactly the staged bf16 P' values the PV product uses.
//  - scores epilogue: exp + store only (atomicAdd + 16-lane reduce dropped).
//  - memset dispatch + lsum buffer + scores->pv lsum dependency all gone.
//  - qkv (R4 form, 780 TF) / convert / 2-wave compact-grid cores unchanged.
//
// MFMA fragment layouts (HW-verified per guide §3):
//  A: lane holds A[m=lane&15][k=(lane>>4)*8+j], j=0..7
//  B: lane holds B[k=(lane>>4)*8+j][n=lane&15]
//  C/D: lane holds D[row=(lane>>4)*4+e][col=lane&15], e=0..3

typedef __attribute__((ext_vector_type(8))) short short8;   // 8 bf16 = 4 VGPRs
typedef __attribute__((ext_vector_type(4))) float floatx4;  // MFMA acc

#define SEQ   2048
#define DMODEL 1024
#define NBATCH 4
#define MTOT  (SEQ * NBATCH)

// Direct global->LDS async copy, 16B per lane. LDS dst is wave-uniform base +
// lane*16 (per-lane scatter NOT supported).
__device__ __forceinline__ void stage16(const __hip_bfloat16* g, __hip_bfloat16* l)
{
  __builtin_amdgcn_global_load_lds(
      (const __attribute__((address_space(1))) void*)g,
      (__attribute__((address_space(3))) void*)l, 16, 0, 0);
}

__device__ __forceinline__ unsigned short bf16_bits(float f)
{
  __hip_bfloat16 h = __float2bfloat16(f);
  return *(unsigned short*)&h;
}

// ---------------------------------------------------------------------------
// One-kernel fp32 -> bf16 convert for all four inputs. Each block: 1024 elems.
__global__ __launch_bounds__(256) void convert_all(
    const float* __restrict__ X,  const float* __restrict__ Wq,
    const float* __restrict__ Wk, const float* __restrict__ Wv,
    __hip_bfloat16* __restrict__ Xb,  __hip_bfloat16* __restrict__ Wqb,
    __hip_bfloat16* __restrict__ Wkb, __hip_bfloat16* __restrict__ Wvb)
{
  const int b = blockIdx.x;
  const float* src; __hip_bfloat16* dst; int rel;
  if (b < 8192)       { src = X;  dst = Xb;  rel = b; }
  else if (b < 9216)  { src = Wq; dst = Wqb; rel = b - 8192; }
  else if (b < 10240) { src = Wk; dst = Wkb; rel = b - 9216; }
  else                { src = Wv; dst = Wvb; rel = b - 10240; }
  const int i = rel * 1024 + threadIdx.x * 4;
  float4 f = *(const float4*)(src + i);
  uint2 o;
  o.x = (unsigned)bf16_bits(f.x) | ((unsigned)bf16_bits(f.y) << 16);
  o.y = (unsigned)bf16_bits(f.z) | ((unsigned)bf16_bits(f.w) << 16);
  *(uint2*)(dst + i) = o;
}

// ---------------------------------------------------------------------------
// Fused QKV projection (R4 version, best measured). A-tile (X) staged once per
// k-iter, three 128x32 B-tiles; 48 MFMA/wave/barrier. Q,K row-major; V -> Vt.
// grid = (8, 64), 256 threads, 32 KB LDS.
__global__ __launch_bounds__(256, 2) void gemm_qkv_fused(
    const __hip_bfloat16* __restrict__ Xb,
    const __hip_bfloat16* __restrict__ Wqb,
    const __hip_bfloat16* __restrict__ Wkb,
    const __hip_bfloat16* __restrict__ Wvb,
    const float* __restrict__ bq, const float* __restrict__ bk, const float* __restrict__ bv,
    __hip_bfloat16* __restrict__ Qb, __hip_bfloat16* __restrict__ Kb, __hip_bfloat16* __restrict__ Vt)
{
  __shared__ __hip_bfloat16 As[128 * 32];
  __shared__ __hip_bfloat16 Bs[3][128 * 32];
  const int m0 = blockIdx.y * 128, n0 = blockIdx.x * 128;
  const int tid  = threadIdx.x;
  const int lane = tid & 63;
  const int wave = tid >> 6;
  const int quad = lane >> 4;
  const int r    = lane & 15;
  const int wm   = (wave >> 1) * 64;
  const int wn   = (wave & 1) * 64;
  const int srow = wave * 16 + (lane >> 2);   // 0..63
  const int scol = (lane & 3) * 8;            // 0,8,16,24

  const __hip_bfloat16* Wp[3] = {Wqb, Wkb, Wvb};

  __hip_bfloat16* lA0 = As + wave * 512;
  __hip_bfloat16* lA1 = As + 2048 + wave * 512;

  const __hip_bfloat16* aR0 = Xb + (size_t)(m0 + srow) * DMODEL + scol;
  const __hip_bfloat16* aR1 = aR0 + (size_t)64 * DMODEL;

  floatx4 acc[3][4][4] = {};

  for (int kt = 0; kt < DMODEL / 32; ++kt) {
    const int k0 = kt * 32;
    stage16(aR0 + k0, lA0);
    stage16(aR1 + k0, lA1);
#pragma unroll
    for (int w = 0; w < 3; ++w) {
      stage16(Wp[w] + (size_t)(n0 + srow) * DMODEL + scol + k0,      Bs[w] + wave * 512);
      stage16(Wp[w] + (size_t)(n0 + 64 + srow) * DMODEL + scol + k0, Bs[w] + 2048 + wave * 512);
    }
    __syncthreads();
    short8 a[4];
#pragma unroll
    for (int i = 0; i < 4; ++i)
      a[i] = *(const short8*)(As + (wm + i * 16 + r) * 32 + quad * 8);
#pragma unroll
    for (int w = 0; w < 3; ++w) {
      short8 b[4];
#pragma unroll
      for (int j = 0; j < 4; ++j)
        b[j] = *(const short8*)(Bs[w] + (wn + j * 16 + r) * 32 + quad * 8);
#pragma unroll
      for (int i = 0; i < 4; ++i)
#pragma unroll
        for (int j = 0; j < 4; ++j)
          acc[w][i][j] = __builtin_amdgcn_mfma_f32_16x16x32_bf16(a[i], b[j], acc[w][i][j], 0, 0, 0);
    }
    __syncthreads();
  }

  // Q, K: row-major stores
  {
    __hip_bfloat16* Op[2] = {Qb, Kb};
    const float* Bp[2] = {bq, bk};
#pragma unroll
    for (int w = 0; w < 2; ++w) {
      __hip_bfloat16* out = Op[w];
#pragma unroll
      for (int j = 0; j < 4; ++j) {
        const int n = n0 + wn + j * 16 + r;
        const float bb = Bp[w][n];
#pragma unroll
        for (int i = 0; i < 4; ++i) {
          const int mbase = m0 + wm + i * 16 + quad * 4;
#pragma unroll
          for (int e = 0; e < 4; ++e)
            out[(size_t)(mbase + e) * DMODEL + n] = __float2bfloat16(acc[w][i][j][e] + bb);
        }
      }
    }
  }
  // V: transposed store Vt[z][d=n][pos], 8B packed per (i,j). z = batch of m0.
  {
    const int z    = m0 >> 11;           // SEQ = 2048
    const int posb = (m0 & (SEQ - 1)) + wm;
    __hip_bfloat16* vt = Vt + (size_t)z * DMODEL * SEQ;
#pragma unroll
    for (int j = 0; j < 4; ++j) {
      const int n = n0 + wn + j * 16 + r;
      const float bb = bv[n];
#pragma unroll
      for (int i = 0; i < 4; ++i) {
        const int pos = posb + i * 16 + quad * 4;
        unsigned long long pk =
            (unsigned long long)bf16_bits(acc[2][i][j][0] + bb)
          | ((unsigned long long)bf16_bits(acc[2][i][j][1] + bb) << 16)
          | ((unsigned long long)bf16_bits(acc[2][i][j][2] + bb) << 32)
          | ((unsigned long long)bf16_bits(acc[2][i][j][3] + bb) << 48);
        *(unsigned long long*)(vt + (size_t)n * SEQ + pos) = pk;
      }
    }
  }
}

// ---------------------------------------------------------------------------
// 2-wave GEMM core: C[64x128] += A * B^T, A/B bf16 row-major [.,K], BK=32.
// 128 threads = 2 waves; wave w owns n-half wn = w*64 (acc [4][4] = 64 AGPR).
// If SUMS: also acc_s[i] += A-frag x ones (row sums of A in C-layout, fp32).
template <bool SUMS>
__device__ __forceinline__ void gemm_core_2w(
    const __hip_bfloat16* __restrict__ A,
    const __hip_bfloat16* __restrict__ B,
    int K, int m0, int n0, int kchunks,
    __hip_bfloat16* As /*64x32*/, __hip_bfloat16* Bs /*128x32*/,
    floatx4 acc[4][4], floatx4 acc_s[4])
{
  const int tid  = threadIdx.x;
  const int lane = tid & 63;
  const int wave = tid >> 6;          // 0..1
  const int quad = lane >> 4;
  const int r    = lane & 15;
  const int wn   = wave * 64;
  const int lrow = lane >> 2;         // 0..15
  const int lcol = (lane & 3) * 8;    // 0,8,16,24

  short8 ones;
#pragma unroll
  for (int t = 0; t < 8; ++t) ones[t] = (short)0x3F80;  // bf16 1.0

  const __hip_bfloat16* aB = A + (size_t)(m0 + wave * 32 + lrow) * K + lcol;
  const __hip_bfloat16* bB = B + (size_t)(n0 + wave * 64 + lrow) * K + lcol;
  __hip_bfloat16* lA = As + wave * 1024;   // 2 chunks of 512
  __hip_bfloat16* lB = Bs + wave * 2048;   // 4 chunks of 512

  for (int kt = 0; kt < kchunks; ++kt) {
    const int k0 = kt * 32;
#pragma unroll
    for (int s = 0; s < 2; ++s)
      stage16(aB + (size_t)(16 * s) * K + k0, lA + s * 512);
#pragma unroll
    for (int s = 0; s < 4; ++s)
      stage16(bB + (size_t)(16 * s) * K + k0, lB + s * 512);
    __syncthreads();
    short8 a[4], b[4];
#pragma unroll
    for (int i = 0; i < 4; ++i) {
      a[i] = *(const short8*)(As + (i * 16 + r) * 32 + quad * 8);
      b[i] = *(const short8*)(Bs + (wn + i * 16 + r) * 32 + quad * 8);
    }
    if (SUMS) {
#pragma unroll
      for (int i = 0; i < 4; ++i)
        acc_s[i] = __builtin_amdgcn_mfma_f32_16x16x32_bf16(a[i], ones, acc_s[i], 0, 0, 0);
    }
#pragma unroll
    for (int i = 0; i < 4; ++i)
#pragma unroll
      for (int j = 0; j < 4; ++j)
        acc[i][j] = __builtin_amdgcn_mfma_f32_16x16x32_bf16(a[i], b[j], acc[i][j], 0, 0, 0);
    __syncthreads();
  }
}

// ---------------------------------------------------------------------------
// Scores: P'[z][q][k] = exp((Qb_z Kb_z^T)[q][k]/32) for k<=q (0 in the masked
// part of diagonal tiles), bf16. No row sums here (pv derives them itself).
// 64m x 128n tiles, 2-wave blocks, COMPACT grid: blockIdx.x = linear id over
// the 272 active (mt,nt) pairs per batch. grid = (272, NBATCH), 128 threads.
__global__ __launch_bounds__(128, 4) void gemm_scores(
    const __hip_bfloat16* __restrict__ Qb, const __hip_bfloat16* __restrict__ Kb,
    __hip_bfloat16* __restrict__ Sb)
{
  const int z = blockIdx.y;
  const int L = blockIdx.x;
  // decode pair index p: largest p with p(p+1) <= L
  int p = (int)((sqrtf(4.0f * (float)L + 1.0f) - 1.0f) * 0.5f);
  while ((p + 1) * (p + 2) <= L) ++p;
  while (p * (p + 1) > L) --p;
  const int o  = L - p * (p + 1);          // 0 .. 2p+1
  const int mt = 2 * p + (o > p ? 1 : 0);
  const int nt = (o > p) ? (o - p - 1) : o;
  const int m0 = mt * 64, n0 = nt * 128;

  __shared__ __hip_bfloat16 As[64 * 32], Bs[128 * 32];
  const __hip_bfloat16* A = Qb + (size_t)z * SEQ * DMODEL;
  const __hip_bfloat16* B = Kb + (size_t)z * SEQ * DMODEL;
  __hip_bfloat16* outp = Sb + (size_t)z * SEQ * SEQ;
  floatx4 acc[4][4] = {};
  floatx4 dummy[4];
  gemm_core_2w<false>(A, B, DMODEL, m0, n0, DMODEL / 32, As, Bs, acc, dummy);

  const int lane = threadIdx.x & 63, wave = threadIdx.x >> 6;
  const int quad = lane >> 4, r = lane & 15;
  const int wn = wave * 64;
  const float scale = 0.03125f;  // 1/sqrt(1024)
#pragma unroll
  for (int i = 0; i < 4; ++i) {
    const int mbase = m0 + i * 16 + quad * 4;
#pragma unroll
    for (int e = 0; e < 4; ++e) {
      const int row = mbase + e;
#pragma unroll
      for (int j = 0; j < 4; ++j) {
        const int n = n0 + wn + j * 16 + r;
        const float pv = (n <= row) ? __expf(acc[i][j][e] * scale) : 0.f;
        outp[(size_t)row * SEQ + n] = __float2bfloat16(pv);
      }
    }
  }
}

// ---------------------------------------------------------------------------
// PV: Out[z][q][d] = (P'_z @ Vt_z^T)[q][d] / rowsum(P'), fp32 out.
// Row sums computed in-kernel via the ones-MFMA (acc_s, C-layout: every column
// of acc_s[i] holds sum_k P'[row][k] for row = m0+i*16+quad*4+e).
// 64m x 128n tiles, 2-wave blocks; K truncated at the diagonal; longest-K
// first. grid = (DMODEL/128=8, SEQ/64=32, 4), 128 threads.
__global__ __launch_bounds__(128, 4) void gemm_pv(
    const __hip_bfloat16* __restrict__ Sb, const __hip_bfloat16* __restrict__ Vt,
    float* __restrict__ Out)
{
  __shared__ __hip_bfloat16 As[64 * 32], Bs[128 * 32];
  const int z = blockIdx.z;
  const int mt = (int)gridDim.y - 1 - (int)blockIdx.y;  // longest-first
  const int m0 = mt * 64, n0 = blockIdx.x * 128;
  const __hip_bfloat16* A = Sb + (size_t)z * SEQ * SEQ;
  const __hip_bfloat16* B = Vt + (size_t)z * DMODEL * SEQ;
  float* outp = Out + (size_t)z * SEQ * DMODEL;

  floatx4 acc[4][4] = {};
  floatx4 acc_s[4] = {};
  const int kchunks = 2 * mt + 2;   // (m0+64)/32: causal truncation
  gemm_core_2w<true>(A, B, SEQ, m0, n0, kchunks, As, Bs, acc, acc_s);

  const int lane = threadIdx.x & 63, wave = threadIdx.x >> 6;
  const int quad = lane >> 4, r = lane & 15;
  const int wn = wave * 64;
#pragma unroll
  for (int i = 0; i < 4; ++i) {
    const int mbase = m0 + i * 16 + quad * 4;
    float inv[4];
#pragma unroll
    for (int e = 0; e < 4; ++e) inv[e] = 1.f / acc_s[i][e];
#pragma unroll
    for (int j = 0; j < 4; ++j) {
      const int n = n0 + wn + j * 16 + r;
#pragma unroll
      for (int e = 0; e < 4; ++e)
        outp[(size_t)(mbase + e) * DMODEL + n] = acc[i][j][e] * inv[e];
    }
  }
}

// ---------------------------------------------------------------------------
extern "C" void kernel_launch(void* const* d_in, const int* in_sizes, int n_in,
                              void* d_out, int out_size, void* d_ws, size_t ws_size,
                              hipStream_t stream)
{
  const float* X  = (const float*)d_in[0];
  const float* Wq = (const float*)d_in[1];
  const float* bq = (const float*)d_in[2];
  const float* Wk = (const float*)d_in[3];
  const float* bk = (const float*)d_in[4];
  const float* Wv = (const float*)d_in[5];
  const float* bv = (const float*)d_in[6];
  float* Out = (float*)d_out;

  // Workspace layout (~103 MB total)
  char* ws = (char*)d_ws;
  size_t off = 0;
  auto alloc = [&](size_t bytes) -> void* {
    void* p = ws + off;
    off += (bytes + 255) & ~(size_t)255;
    return p;
  };
  __hip_bfloat16* Xb  = (__hip_bfloat16*)alloc((size_t)MTOT * DMODEL * 2);    // 16 MB
  __hip_bfloat16* Wqb = (__hip_bfloat16*)alloc((size_t)DMODEL * DMODEL * 2);  // 2 MB
  __hip_bfloat16* Wkb = (__hip_bfloat16*)alloc((size_t)DMODEL * DMODEL * 2);
  __hip_bfloat16* Wvb = (__hip_bfloat16*)alloc((size_t)DMODEL * DMODEL * 2);
  __hip_bfloat16* Qb  = (__hip_bfloat16*)alloc((size_t)MTOT * DMODEL * 2);    // 16 MB
  __hip_bfloat16* Kb  = (__hip_bfloat16*)alloc((size_t)MTOT * DMODEL * 2);    // 16 MB
  __hip_bfloat16* Vt  = (__hip_bfloat16*)alloc((size_t)MTOT * DMODEL * 2);    // 16 MB
  __hip_bfloat16* Sb  = (__hip_bfloat16*)alloc((size_t)NBATCH * SEQ * SEQ * 2); // 32 MB
  (void)ws_size; (void)in_sizes; (void)n_in; (void)out_size;

  // 1) converts (one kernel)
  convert_all<<<11264, 256, 0, stream>>>(X, Wq, Wk, Wv, Xb, Wqb, Wkb, Wvb);
  // 2) fused QKV projection (128x128); V written transposed
  gemm_qkv_fused<<<dim3(DMODEL / 128, MTOT / 128), 256, 0, stream>>>(
      Xb, Wqb, Wkb, Wvb, bq, bk, bv, Qb, Kb, Vt);
  // 3) scores: 2-wave 64x128 tiles, compact grid, P' = exp(s)
  gemm_scores<<<dim3(272, NBATCH), 128, 0, stream>>>(Qb, Kb, Sb);
  // 4) PV: 2-wave 64x128 tiles, longest-first, in-kernel row sums + normalize
  gemm_pv<<<dim3(DMODEL / 128, SEQ / 64, NBATCH), 128, 0, stream>>>(Sb, Vt, Out);
}